// Round 3
// baseline (390.344 us; speedup 1.0000x reference)
//
#include <hip/hip_runtime.h>

// SelfAttention: B=4, S=2048, D=1024, fp32 in/out.
// q=x@Wq^T+bq, k=..., v=...; out = softmax(q k^T) @ v   (no 1/sqrt(d) scale)
//
// Precision plan (all GEMM cores in MFMA):
//  - q/k projections: 2-digit i8 x 2-digit i8, ALL 4 digit products kept
//    (exact integer accumulation). x = d0*2^-4 + d1*2^-12,
//    W = e0*2^-9 + e1*2^-17. delta-q ~ 1.2e-4 std.
//  - q/k requantized to 2 i8 digits (2^-4 / 2^-12) in the epilogue.
//  - scores: 2-digit i8 (M=d0d0 2^-8, X=cross 2^-16, Y=d1d1 2^-24). Exact.
//  - v projection: single bf16 MFMA (dv ~1.4e-3, harmless); PV GEMM in f16.
// P has its own dense buffer (R4 post-mortem: in-place P alias breaks replay).
// R8: fragment-linear LDS via pre-swizzled global source (bank conflicts 4.19M -> 0).
// R9: counted vmcnt + raw s_barrier pipeline (T4): qk 136->106us, MfmaUtil 21->27%.
// R10: FETCH_SIZE showed 8x HBM re-fetch (qk 135MB vs ~20MB ideal): flat%8 = n
//     = XCD id, so every XCD walked ALL m-rows, re-fetching A-tiles per XCD and
//     making stage loads ~900-cyc HBM misses (uncoverable by depth-1 prefetch).
//     Fix: T1 XCD-aware bijective swizzle on all 4 GEMMs — each XCD gets a
//     contiguous chunk (n fastest), A+B working set ~4MB fits per-XCD L2;
//     stage loads become ~200-cyc L2 hits, covered by the MFMA phase.

#define Bb 4
#define Ss 2048
#define Dd 1024
#define Mtot 8192  // B*S

typedef __bf16 bf16x8 __attribute__((ext_vector_type(8)));
typedef _Float16 f16x8 __attribute__((ext_vector_type(8)));
typedef float f32x4 __attribute__((ext_vector_type(4)));
typedef int i32x4 __attribute__((ext_vector_type(4)));
typedef unsigned short u16;
typedef unsigned int u32;
typedef unsigned char u8;
typedef u16 u16x8 __attribute__((ext_vector_type(8)));
typedef u16 u16x4 __attribute__((ext_vector_type(4)));
typedef void __attribute__((address_space(1))) gvoid_t;
typedef void __attribute__((address_space(3))) svoid_t;

// ---- digit scales (all powers of two; products align exactly) ----
#define XC 0.0625f
#define XCI 16.f
#define XFI 4096.f
#define WC 1.953125e-3f
#define WCI 512.f
#define WFI 131072.f
// projection accumulator scales
#define SM_P 1.220703125e-4f          // 2^-13
#define SX_P 4.76837158203125e-7f     // 2^-21
#define SY_P 1.862645149230957e-9f    // 2^-29
// score accumulator scales
#define S00 3.90625e-3f               // 2^-8
#define S01 1.52587890625e-5f         // 2^-16
#define S11 5.9604644775390625e-8f    // 2^-24

__device__ __forceinline__ void gl_lds16(const void* g, void* l) {
  __builtin_amdgcn_global_load_lds((gvoid_t*)g, (svoid_t*)l, 16, 0, 0);
}

__device__ __forceinline__ u16 f2bf(float f) {  // RNE float->bf16
  u32 u = __builtin_bit_cast(u32, f);
  u = (u + 0x7FFFu + ((u >> 16) & 1u)) >> 16;
  return (u16)u;
}
__device__ __forceinline__ u16 f2h(float f) {
  return __builtin_bit_cast(u16, (_Float16)f);
}
__device__ __forceinline__ bf16x8 frag_ld(const char* p) {
  u16x8 v = *(const u16x8*)p;
  return __builtin_bit_cast(bf16x8, v);
}
__device__ __forceinline__ f16x8 frag_ld_h(const char* p) {
  u16x8 v = *(const u16x8*)p;
  return __builtin_bit_cast(f16x8, v);
}
__device__ __forceinline__ f32x4 mfma_bf16(bf16x8 a, bf16x8 b, f32x4 c) {
  return __builtin_amdgcn_mfma_f32_16x16x32_bf16(a, b, c, 0, 0, 0);
}
__device__ __forceinline__ i32x4 mfma_i8(i32x4 a, i32x4 b, i32x4 c) {
  return __builtin_amdgcn_mfma_i32_16x16x64_i8(a, b, c, 0, 0, 0);
}
// split v into two clamped i8 digits: v ~= d0*cs + d1*(1/fi)
__device__ __forceinline__ void dig2(float v, float cs, float ci, float fi,
                                     int& d0, int& d1) {
  float t = fminf(fmaxf(v * ci, -127.f), 127.f);
  d0 = __float2int_rn(t);
  float res = v - (float)d0 * cs;
  float u = fminf(fmaxf(res * fi, -127.f), 127.f);
  d1 = __float2int_rn(u);
}

// T1: bijective XCD-aware block swizzle. Each of the 8 XCDs gets a contiguous
// chunk of N/8 blocks, n (bx) fastest -> A-row-tiles fetched once per chip,
// B-tiles + A working set resident in the XCD's private 4MB L2.
// Requires GX,GY powers of 2 and N%8==0 (all grids here qualify).
template <int GX, int GY, int GZ>
__device__ __forceinline__ void xcd_swz(int& bx, int& by, int& bz) {
  constexpr int N = GX * GY * GZ;
  int flat = (int)blockIdx.x + GX * ((int)blockIdx.y + GY * (int)blockIdx.z);
  int s = (flat & 7) * (N >> 3) + (flat >> 3);
  bx = s & (GX - 1);
  by = (s / GX) & (GY - 1);
  bz = s / (GX * GY);
}

// pipeline sync helpers (T4): wait with N loads still allowed in flight,
// then raw barrier. sched_barrier(0) pins LDS reads below the barrier.
__device__ __forceinline__ void wait_bar_keep8() {
  asm volatile("s_waitcnt vmcnt(8)" ::: "memory");
  __builtin_amdgcn_s_barrier();
  __builtin_amdgcn_sched_barrier(0);
}
__device__ __forceinline__ void wait_bar_keep4() {
  asm volatile("s_waitcnt vmcnt(4)" ::: "memory");
  __builtin_amdgcn_s_barrier();
  __builtin_amdgcn_sched_barrier(0);
}
__device__ __forceinline__ void wait_bar_drain() {
  asm volatile("s_waitcnt vmcnt(0)" ::: "memory");
  __builtin_amdgcn_s_barrier();
  __builtin_amdgcn_sched_barrier(0);
}
__device__ __forceinline__ void end_bar() {
  __builtin_amdgcn_sched_barrier(0);
  __builtin_amdgcn_s_barrier();
}

// Fragment-linear stager: tile of (ROUNDS*64/C) rows x (C*16) bytes.
// LDS destination is lane-linear (required by global_load_lds); the GLOBAL
// source address is permuted so that each 16-row subtile is stored as
// [chunk-group h][chunk lk][row lr] 16B chunks. A wave's MFMA fragment read
// is then  subtile_base + h*1024 + lane*16  -> conflict-free.
template <int ROUNDS, int C>  // C = 16B chunks per row (row = C*16 bytes)
__device__ __forceinline__ void stageF(const char* g, long row0, long ldb,
                                       long k0b, char* l, int tid) {
#pragma unroll
  for (int r = 0; r < ROUNDS; ++r) {
    int s = r * 256 + tid;        // 16B slot index (lane-linear in LDS)
    int sub = s / (16 * C);       // 16-row subtile
    int t = s % (16 * C);
    int h = t >> 6;               // chunk-group of 4
    int lk = (t >> 4) & 3;
    int lr = t & 15;
    gl_lds16(g + (row0 + sub * 16 + lr) * ldb + k0b + (h * 4 + lk) * 16,
             l + s * 16);
  }
}

// ---------------------------------------------------------------- converts
__global__ void __launch_bounds__(256) convert_all(
    const float* __restrict__ x, const float* __restrict__ Wq,
    const float* __restrict__ Wk, const float* __restrict__ Wv,
    u16* __restrict__ xh, u8* __restrict__ xd0, u8* __restrict__ xd1,
    u8* __restrict__ wq0, u8* __restrict__ wq1,
    u8* __restrict__ wk0, u8* __restrict__ wk1,
    u16* __restrict__ wvh) {
  long b = blockIdx.x;
  if (b < 8192) {
    long i = b * 256 + threadIdx.x;
    f32x4 v = ((const f32x4*)x)[i];
    u16x4 h;
    u32 p0 = 0, p1 = 0;
#pragma unroll
    for (int j = 0; j < 4; ++j) {
      h[j] = f2bf(v[j]);
      int d0, d1;
      dig2(v[j], XC, XCI, XFI, d0, d1);
      p0 |= ((u32)(d0 & 255)) << (8 * j);
      p1 |= ((u32)(d1 & 255)) << (8 * j);
    }
    ((u16x4*)xh)[i] = h;
    ((u32*)xd0)[i] = p0;
    ((u32*)xd1)[i] = p1;
  } else if (b < 10240) {
    int w = (int)((b - 8192) >> 10);  // 0=q, 1=k
    const float* src = w ? Wk : Wq;
    u8* o0 = w ? wk0 : wq0;
    u8* o1 = w ? wk1 : wq1;
    long i = ((b - 8192) & 1023) * 256 + threadIdx.x;
    f32x4 v = ((const f32x4*)src)[i];
    u32 p0 = 0, p1 = 0;
#pragma unroll
    for (int j = 0; j < 4; ++j) {
      int d0, d1;
      dig2(v[j], WC, WCI, WFI, d0, d1);
      p0 |= ((u32)(d0 & 255)) << (8 * j);
      p1 |= ((u32)(d1 & 255)) << (8 * j);
    }
    ((u32*)o0)[i] = p0;
    ((u32*)o1)[i] = p1;
  } else {
    long i = (b - 10240) * 256 + threadIdx.x;
    f32x4 v = ((const f32x4*)Wv)[i];
    u16x4 h;
#pragma unroll
    for (int j = 0; j < 4; ++j) h[j] = f2bf(v[j]);
    ((u16x4*)wvh)[i] = h;
  }
}

// ---------------------------------------------------------------- q/k GEMM
// 128x128 block, 4 waves (2x2), wave-tile 64x64.
// K-64 double-buffered, counted-vmcnt pipeline: 2 x 32KB (A0 A1 B0 B1).
__global__ void __launch_bounds__(256) qk_gemm(
    const u8* __restrict__ xd0, const u8* __restrict__ xd1,
    const u8* __restrict__ wq0, const u8* __restrict__ wq1,
    const u8* __restrict__ wk0, const u8* __restrict__ wk1,
    const float* __restrict__ bq, const float* __restrict__ bk,
    u8* __restrict__ q0, u8* __restrict__ q1,
    u8* __restrict__ kd0, u8* __restrict__ kd1) {
  __shared__ char lds[65536];
  const int tid = threadIdx.x;
  int bx, by, bz;
  xcd_swz<8, 64, 2>(bx, by, bz);
  const int z = bz;
  const long m0 = (long)by * 128;
  const int n0 = bx * 128;
  const int wave = tid >> 6, lane = tid & 63;
  const int wm = wave >> 1, wn = wave & 1;
  const int lr = lane & 15, lk = lane >> 4;

  const u8* w0 = z ? wk0 : wq0;
  const u8* w1 = z ? wk1 : wq1;
  const float* bias = z ? bk : bq;
  u8* o0 = z ? kd0 : q0;
  u8* o1 = z ? kd1 : q1;

  i32x4 accM[4][4] = {};  // d0*e0  scale 2^-13
  i32x4 accX[4][4] = {};  // cross  scale 2^-21
  i32x4 accY[4][4] = {};  // d1*e1  scale 2^-29

  auto stage = [&](char* L, int kk) {  // 8 global_load_lds per thread
    stageF<2, 4>((const char*)xd0, m0, Dd, kk, L + 0, tid);
    stageF<2, 4>((const char*)xd1, m0, Dd, kk, L + 8192, tid);
    stageF<2, 4>((const char*)w0, n0, Dd, kk, L + 16384, tid);
    stageF<2, 4>((const char*)w1, n0, Dd, kk, L + 24576, tid);
  };
  auto compute = [&](const char* L) {
    i32x4 b0[4], b1[4];
#pragma unroll
    for (int nt = 0; nt < 4; ++nt) {
      int rb = (wn * 4 + nt) * 1024 + lane * 16;
      b0[nt] = *(const i32x4*)(L + 16384 + rb);
      b1[nt] = *(const i32x4*)(L + 24576 + rb);
    }
    __builtin_amdgcn_s_setprio(1);
#pragma unroll
    for (int mt = 0; mt < 4; ++mt) {
      int ra = (wm * 4 + mt) * 1024 + lane * 16;
      i32x4 a0 = *(const i32x4*)(L + ra);
      i32x4 a1 = *(const i32x4*)(L + 8192 + ra);
#pragma unroll
      for (int nt = 0; nt < 4; ++nt) {
        accM[mt][nt] = mfma_i8(a0, b0[nt], accM[mt][nt]);
        accX[mt][nt] = mfma_i8(a0, b1[nt], accX[mt][nt]);
        accX[mt][nt] = mfma_i8(a1, b0[nt], accX[mt][nt]);
        accY[mt][nt] = mfma_i8(a1, b1[nt], accY[mt][nt]);
      }
    }
    __builtin_amdgcn_s_setprio(0);
  };

  stage(lds, 0);
  for (int t = 0; t < Dd / 64 - 1; ++t) {
    char* L = lds + (t & 1) * 32768;
    stage(lds + ((t + 1) & 1) * 32768, (t + 1) * 64);  // stays in flight
    wait_bar_keep8();                                  // buf[t] ready
    compute(L);
    end_bar();                                         // buf[t] reads done
  }
  {
    char* L = lds + ((Dd / 64 - 1) & 1) * 32768;
    wait_bar_drain();
    compute(L);
  }

#pragma unroll
  for (int mt = 0; mt < 4; ++mt)
#pragma unroll
    for (int nt = 0; nt < 4; ++nt)
#pragma unroll
      for (int r = 0; r < 4; ++r) {
        long gm = m0 + wm * 64 + mt * 16 + lk * 4 + r;
        int e = n0 + wn * 64 + nt * 16 + lr;
        float v = (float)accM[mt][nt][r] * SM_P +
                  (float)accX[mt][nt][r] * SX_P +
                  (float)accY[mt][nt][r] * SY_P + bias[e];
        int d0, d1;
        dig2(v, XC, XCI, XFI, d0, d1);
        long idx = gm * Dd + e;
        o0[idx] = (u8)d0;
        o1[idx] = (u8)d1;
      }
}

// ---------------------------------------------------------------- v GEMM
// K-32 double-buffered counted-vmcnt pipeline: 2 x 16KB (A | B).
__global__ void __launch_bounds__(256) v_gemm(
    const u16* __restrict__ xh, const u16* __restrict__ wvh,
    const float* __restrict__ bv, u16* __restrict__ vt) {
  __shared__ char lds[32768];
  const int tid = threadIdx.x;
  int bx, by, bz;
  xcd_swz<8, 64, 1>(bx, by, bz);
  const long m0 = (long)by * 128;
  const int n0 = bx * 128;
  const int wave = tid >> 6, lane = tid & 63;
  const int wm = wave >> 1, wn = wave & 1;
  const int lr = lane & 15, lk = lane >> 4;

  f32x4 acc[4][4] = {};

  auto stage = [&](char* L, int k0) {  // 4 global_load_lds per thread
    stageF<2, 4>((const char*)xh, m0, (long)Dd * 2, (long)k0 * 2, L + 0, tid);
    stageF<2, 4>((const char*)wvh, n0, (long)Dd * 2, (long)k0 * 2, L + 8192, tid);
  };
  auto compute = [&](const char* L) {
    bf16x8 af[4], bfr[4];
#pragma unroll
    for (int i = 0; i < 4; ++i) {
      int ra = (wm * 4 + i) * 1024 + lane * 16;
      int rb = (wn * 4 + i) * 1024 + lane * 16;
      af[i] = frag_ld(L + ra);
      bfr[i] = frag_ld(L + 8192 + rb);
    }
    __builtin_amdgcn_s_setprio(1);
#pragma unroll
    for (int mt = 0; mt < 4; ++mt)
#pragma unroll
      for (int nt = 0; nt < 4; ++nt)
        acc[mt][nt] = mfma_bf16(af[mt], bfr[nt], acc[mt][nt]);
    __builtin_amdgcn_s_setprio(0);
  };

  stage(lds, 0);
  for (int t = 0; t < Dd / 32 - 1; ++t) {
    char* L = lds + (t & 1) * 16384;
    stage(lds + ((t + 1) & 1) * 16384, (t + 1) * 32);
    wait_bar_keep4();
    compute(L);
    end_bar();
  }
  {
    char* L = lds + ((Dd / 32 - 1) & 1) * 16384;
    wait_bar_drain();
    compute(L);
  }

#pragma unroll
  for (int mt = 0; mt < 4; ++mt)
#pragma unroll
    for (int nt = 0; nt < 4; ++nt)
#pragma unroll
      for (int r = 0; r < 4; ++r) {
        long gm = m0 + wm * 64 + mt * 16 + lk * 4 + r;
        int e = n0 + wn * 64 + nt * 16 + lr;
        float v = acc[mt][nt][r] + bv[e];
        long b = gm >> 11, s = gm & 2047;
        vt[(b * Dd + e) * (long)Ss + s] = f2h(v);
      }
}

// ---------------------------------------------------------------- scores GEMM
// same K-64 counted-vmcnt structure as qk_gemm.
__global__ void __launch_bounds__(256) score_gemm(
    const u8* __restrict__ q0, const u8* __restrict__ q1,
    const u8* __restrict__ kd0, const u8* __restrict__ kd1,
    float* __restrict__ scores) {
  __shared__ char lds[65536];
  const int tid = threadIdx.x;
  int bx, by, bz;
  xcd_swz<16, 16, 4>(bx, by, bz);
  const int z = bz;  // batch
  const long base = (long)z * Ss * Dd;
  const long m0 = (long)by * 128;
  const int n0 = bx * 128;
  const int wave = tid >> 6, lane = tid & 63;
  const int wm = wave >> 1, wn = wave & 1;
  const int lr = lane & 15, lk = lane >> 4;

  i32x4 accM[4][4] = {};  // d0*d0   scale 2^-8
  i32x4 accX[4][4] = {};  // cross   scale 2^-16
  i32x4 accY[4][4] = {};  // d1*d1   scale 2^-24

  auto stage = [&](char* L, int kk) {  // 8 global_load_lds per thread
    stageF<2, 4>((const char*)q0 + base, m0, Dd, kk, L + 0, tid);
    stageF<2, 4>((const char*)q1 + base, m0, Dd, kk, L + 8192, tid);
    stageF<2, 4>((const char*)kd0 + base, n0, Dd, kk, L + 16384, tid);
    stageF<2, 4>((const char*)kd1 + base, n0, Dd, kk, L + 24576, tid);
  };
  auto compute = [&](const char* L) {
    i32x4 b0[4], b1[4];
#pragma unroll
    for (int nt = 0; nt < 4; ++nt) {
      int rb = (wn * 4 + nt) * 1024 + lane * 16;
      b0[nt] = *(const i32x4*)(L + 16384 + rb);
      b1[nt] = *(const i32x4*)(L + 24576 + rb);
    }
    __builtin_amdgcn_s_setprio(1);
#pragma unroll
    for (int mt = 0; mt < 4; ++mt) {
      int ra = (wm * 4 + mt) * 1024 + lane * 16;
      i32x4 a0 = *(const i32x4*)(L + ra);
      i32x4 a1 = *(const i32x4*)(L + 8192 + ra);
#pragma unroll
      for (int nt = 0; nt < 4; ++nt) {
        accM[mt][nt] = mfma_i8(a0, b0[nt], accM[mt][nt]);
        accX[mt][nt] = mfma_i8(a0, b1[nt], accX[mt][nt]);
        accX[mt][nt] = mfma_i8(a1, b0[nt], accX[mt][nt]);
        accY[mt][nt] = mfma_i8(a1, b1[nt], accY[mt][nt]);
      }
    }
    __builtin_amdgcn_s_setprio(0);
  };

  stage(lds, 0);
  for (int t = 0; t < Dd / 64 - 1; ++t) {
    char* L = lds + (t & 1) * 32768;
    stage(lds + ((t + 1) & 1) * 32768, (t + 1) * 64);
    wait_bar_keep8();
    compute(L);
    end_bar();
  }
  {
    char* L = lds + ((Dd / 64 - 1) & 1) * 32768;
    wait_bar_drain();
    compute(L);
  }

  float* srow = scores + (long)z * Ss * Ss;
#pragma unroll
  for (int mt = 0; mt < 4; ++mt)
#pragma unroll
    for (int nt = 0; nt < 4; ++nt)
#pragma unroll
      for (int r = 0; r < 4; ++r) {
        long i = m0 + wm * 64 + mt * 16 + lk * 4 + r;
        int j = n0 + wn * 64 + nt * 16 + lr;
        srow[i * Ss + j] = (float)accM[mt][nt][r] * S00 +
                           (float)accX[mt][nt][r] * S01 +
                           (float)accY[mt][nt][r] * S11;
      }
}

// ---------------------------------------------------------------- softmax
__global__ void __launch_bounds__(256) softmax_rows(const float* __restrict__ scores,
                                                    u16* __restrict__ P) {
  const long r = blockIdx.x;
  const float* row = scores + r * Ss;
  u16* prow = P + r * Ss;
  const int t = threadIdx.x;
  const int wave = t >> 6, lane = t & 63;
  f32x4 v0 = ((const f32x4*)row)[t * 2];
  f32x4 v1 = ((const f32x4*)row)[t * 2 + 1];
  float a[8];
#pragma unroll
  for (int j = 0; j < 4; ++j) { a[j] = v0[j]; a[4 + j] = v1[j]; }

  float m = a[0];
#pragma unroll
  for (int j = 1; j < 8; ++j) m = fmaxf(m, a[j]);
#pragma unroll
  for (int off = 32; off >= 1; off >>= 1) m = fmaxf(m, __shfl_xor(m, off));
  __shared__ float red[4];
  if (lane == 0) red[wave] = m;
  __syncthreads();
  m = fmaxf(fmaxf(red[0], red[1]), fmaxf(red[2], red[3]));

  float e[8];
  float s = 0.f;
#pragma unroll
  for (int j = 0; j < 8; ++j) { e[j] = __expf(a[j] - m); s += e[j]; }
#pragma unroll
  for (int off = 32; off >= 1; off >>= 1) s += __shfl_xor(s, off);
  __syncthreads();
  if (lane == 0) red[wave] = s;
  __syncthreads();
  s = red[0] + red[1] + red[2] + red[3];
  float inv = 1.0f / s;

  u16x8 pk;
#pragma unroll
  for (int j = 0; j < 8; ++j) pk[j] = f2h(e[j] * inv);
  ((u16x8*)prow)[t] = pk;
}

// ---------------------------------------------------------------- PV GEMM
// K-32 double-buffered counted-vmcnt pipeline, fragment-linear LDS.
__global__ void __launch_bounds__(256) pv_gemm(const u16* __restrict__ P,
                                               const u16* __restrict__ vt,
                                               float* __restrict__ out) {
  __shared__ char lds[32768];
  const int tid = threadIdx.x;
  int bx, by, bz;
  xcd_swz<8, 16, 4>(bx, by, bz);
  const int z = bz;  // batch
  const u16* A = P + (long)z * Ss * Ss;    // dense [2048][2048] f16
  const u16* Bp = vt + (long)z * Dd * Ss;  // [1024][2048]
  const long m0 = (long)by * 128;
  const int n0 = bx * 128;

  const int wave = tid >> 6, lane = tid & 63;
  const int wm = wave >> 1, wn = wave & 1;
  const int lr = lane & 15, lk = lane >> 4;

  f32x4 acc[4][4] = {};

  auto stage = [&](char* L, int k0) {  // 4 global_load_lds per thread
    stageF<2, 4>((const char*)A, m0, (long)Ss * 2, (long)k0 * 2, L + 0, tid);
    stageF<2, 4>((const char*)Bp, n0, (long)Ss * 2, (long)k0 * 2, L + 8192, tid);
  };
  auto compute = [&](const char* L) {
    f16x8 af[4], bfr[4];
#pragma unroll
    for (int i = 0; i < 4; ++i) {
      int ra = (wm * 4 + i) * 1024 + lane * 16;
      int rb = (wn * 4 + i) * 1024 + lane * 16;
      af[i] = frag_ld_h(L + ra);
      bfr[i] = frag_ld_h(L + 8192 + rb);
    }
    __builtin_amdgcn_s_setprio(1);
#pragma unroll
    for (int mt = 0; mt < 4; ++mt)
#pragma unroll
      for (int nt = 0; nt < 4; ++nt)
        acc[mt][nt] = __builtin_amdgcn_mfma_f32_16x16x32_f16(af[mt], bfr[nt], acc[mt][nt], 0, 0, 0);
    __builtin_amdgcn_s_setprio(0);
  };

  stage(lds, 0);
  for (int t = 0; t < Ss / 32 - 1; ++t) {
    char* L = lds + (t & 1) * 16384;
    stage(lds + ((t + 1) & 1) * 16384, (t + 1) * 32);
    wait_bar_keep4();
    compute(L);
    end_bar();
  }
  {
    char* L = lds + ((Ss / 32 - 1) & 1) * 16384;
    wait_bar_drain();
    compute(L);
  }

  float* orow = out + (long)z * Ss * Dd;
#pragma unroll
  for (int mt = 0; mt < 4; ++mt)
#pragma unroll
    for (int nt = 0; nt < 4; ++nt)
#pragma unroll
      for (int r = 0; r < 4; ++r) {
        long i = m0 + wm * 64 + mt * 16 + lk * 4 + r;
        int e = n0 + wn * 64 + nt * 16 + lr;
        orow[i * Dd + e] = acc[mt][nt][r];
      }
}

// ---------------------------------------------------------------- launch
extern "C" void kernel_launch(void* const* d_in, const int* in_sizes, int n_in,
                              void* d_out, int out_size, void* d_ws, size_t ws_size,
                              hipStream_t stream) {
  const float* x = (const float*)d_in[0];
  const float* Wq = (const float*)d_in[1];
  const float* bq = (const float*)d_in[2];
  const float* Wk = (const float*)d_in[3];
  const float* bk = (const float*)d_in[4];
  const float* Wv = (const float*)d_in[5];
  const float* bv = (const float*)d_in[6];
  float* out = (float*)d_out;

  // workspace carve (~150 MiB)
  char* p = (char*)d_ws;
  float* scores = (float*)p;           // 64 MB; x buffers aliased underneath
  u16* xh = (u16*)p;                   //   (dead before scores written)
  u8* xd0 = (u8*)(p + 16777216);
  u8* xd1 = (u8*)(p + 25165824);
  p += 67108864;
  u8* q0 = (u8*)p; p += 8388608;
  u8* q1 = (u8*)p; p += 8388608;
  u8* kd0 = (u8*)p; p += 8388608;
  u8* kd1 = (u8*)p; p += 8388608;
  u16* Pbuf = (u16*)p; p += 33554432;  // dense f16 P [4][2048][2048]
  u16* vt = (u16*)p; p += 16777216;
  u8* wq0 = (u8*)p; p += 1048576;
  u8* wq1 = (u8*)p; p += 1048576;
  u8* wk0 = (u8*)p; p += 1048576;
  u8* wk1 = (u8*)p; p += 1048576;
  u16* wvh = (u16*)p; p += 2097152;

  // 1. converts
  convert_all<<<dim3(11264), dim3(256), 0, stream>>>(
      x, Wq, Wk, Wv, xh, xd0, xd1, wq0, wq1, wk0, wk1, wvh);

  // 2a. q/k projections (i8 digit GEMM, counted-vmcnt pipeline, XCD-swizzled)
  qk_gemm<<<dim3(Dd / 128, Mtot / 128, 2), dim3(256), 0, stream>>>(
      xd0, xd1, wq0, wq1, wk0, wk1, bq, bk, q0, q1, kd0, kd1);

  // 2b. v projection (bf16, transposed f16 out)
  v_gemm<<<dim3(Dd / 128, Mtot / 128), dim3(256), 0, stream>>>(xh, wvh, bv, vt);

  // 3. scores = q k^T (pure i8, counted-vmcnt pipeline, XCD-swizzled)
  score_gemm<<<dim3(Ss / 128, Ss / 128, Bb), dim3(256), 0, stream>>>(
      q0, q1, kd0, kd1, scores);

  // 4. softmax rows -> dense P
  softmax_rows<<<dim3(Bb * Ss), dim3(256), 0, stream>>>(scores, Pbuf);

  // 5. out = P @ v
  pv_gemm<<<dim3(Dd / 128, Ss / 128, Bb), dim3(256), 0, stream>>>(Pbuf, vt, out);
}

// Round 4
// 374.529 us; speedup vs baseline: 1.0422x; 1.0422x over previous
//
#include <hip/hip_runtime.h>

// SelfAttention: B=4, S=2048, D=1024, fp32 in/out.
// q=x@Wq^T+bq, k=..., v=...; out = softmax(q k^T) @ v   (no 1/sqrt(d) scale)
//
// R11 ALGEBRAIC RESTRUCTURE:
//   scores = q k^T = x G x^T + u 1^T + 1 w^T + c,
//   G = Wq^T Wk (1024x1024, precomputed), u = x (Wq^T bk) + c, w = x (Wk^T bq),
//   c = bq.bk.  This replaces BOTH q and k projections (two 8192x1024x1024
//   digit GEMMs, ~126us) with ONE (t = x G), and score = t x^T (B-side = x
//   digits, already available).  Biases become exact f32 epilogue adds.
// Precision: G via 4-product i8 digit GEMM (K-split 4 + f32 reduce), err ~5e-6;
//   t digitized with the same (2^-4, 2^-12) scales as q was; score scales
//   unchanged (2^-8/-16/-24).  Expected absmax ~unchanged (f16 PV dominates).
// Carried from earlier rounds:
//   R8: fragment-linear LDS via pre-swizzled global source (bank conflicts 0).
//   R9: counted vmcnt + raw s_barrier pipeline (T4).
//   R10: XCD-aware bijective block swizzle (FETCH 135->29MB on qk).
// i8 kernels are LDS-BW-bound (~40% MfmaUtil ceiling at 64x64 wave-tile);
// this round cuts total i8 work ~25% instead of fighting that ceiling.

#define Bb 4
#define Ss 2048
#define Dd 1024
#define Mtot 8192  // B*S

typedef __bf16 bf16x8 __attribute__((ext_vector_type(8)));
typedef _Float16 f16x8 __attribute__((ext_vector_type(8)));
typedef float f32x4 __attribute__((ext_vector_type(4)));
typedef int i32x4 __attribute__((ext_vector_type(4)));
typedef signed char i8x16 __attribute__((ext_vector_type(16)));
typedef unsigned short u16;
typedef unsigned int u32;
typedef unsigned char u8;
typedef u16 u16x8 __attribute__((ext_vector_type(8)));
typedef u16 u16x4 __attribute__((ext_vector_type(4)));
typedef void __attribute__((address_space(1))) gvoid_t;
typedef void __attribute__((address_space(3))) svoid_t;

// ---- digit scales (all powers of two; products align exactly) ----
#define XC 0.0625f
#define XCI 16.f
#define XFI 4096.f
#define WC 1.953125e-3f               // 2^-9
#define WCI 512.f
#define WFI 131072.f
#define W1S 7.62939453125e-6f         // 2^-17 (second W digit scale)
// t = x*G accumulator scales (x digits 2^-4/2^-12, G digits 2^-9/2^-17)
#define SM_P 1.220703125e-4f          // 2^-13
#define SX_P 4.76837158203125e-7f     // 2^-21
#define SY_P 1.862645149230957e-9f    // 2^-29
// score (t x^T) accumulator scales
#define S00 3.90625e-3f               // 2^-8
#define S01 1.52587890625e-5f         // 2^-16
#define S11 5.9604644775390625e-8f    // 2^-24
// G = Wq^T Wk accumulator scales (W digits both sides)
#define SG00 3.814697265625e-6f       // 2^-18
#define SG01 1.4901161193847656e-8f   // 2^-26
#define SG11 5.820766091346741e-11f   // 2^-34

__device__ __forceinline__ void gl_lds16(const void* g, void* l) {
  __builtin_amdgcn_global_load_lds((gvoid_t*)g, (svoid_t*)l, 16, 0, 0);
}

__device__ __forceinline__ u16 f2bf(float f) {  // RNE float->bf16
  u32 u = __builtin_bit_cast(u32, f);
  u = (u + 0x7FFFu + ((u >> 16) & 1u)) >> 16;
  return (u16)u;
}
__device__ __forceinline__ u16 f2h(float f) {
  return __builtin_bit_cast(u16, (_Float16)f);
}
__device__ __forceinline__ bf16x8 frag_ld(const char* p) {
  u16x8 v = *(const u16x8*)p;
  return __builtin_bit_cast(bf16x8, v);
}
__device__ __forceinline__ f16x8 frag_ld_h(const char* p) {
  u16x8 v = *(const u16x8*)p;
  return __builtin_bit_cast(f16x8, v);
}
__device__ __forceinline__ f32x4 mfma_bf16(bf16x8 a, bf16x8 b, f32x4 c) {
  return __builtin_amdgcn_mfma_f32_16x16x32_bf16(a, b, c, 0, 0, 0);
}
__device__ __forceinline__ i32x4 mfma_i8(i32x4 a, i32x4 b, i32x4 c) {
  return __builtin_amdgcn_mfma_i32_16x16x64_i8(a, b, c, 0, 0, 0);
}
// split v into two clamped i8 digits: v ~= d0*cs + d1*(1/fi)
__device__ __forceinline__ void dig2(float v, float cs, float ci, float fi,
                                     int& d0, int& d1) {
  float t = fminf(fmaxf(v * ci, -127.f), 127.f);
  d0 = __float2int_rn(t);
  float res = v - (float)d0 * cs;
  float u = fminf(fmaxf(res * fi, -127.f), 127.f);
  d1 = __float2int_rn(u);
}

// T1: bijective XCD-aware block swizzle (pow2 grids, N%8==0).
template <int GX, int GY, int GZ>
__device__ __forceinline__ void xcd_swz(int& bx, int& by, int& bz) {
  constexpr int N = GX * GY * GZ;
  int flat = (int)blockIdx.x + GX * ((int)blockIdx.y + GY * (int)blockIdx.z);
  int s = (flat & 7) * (N >> 3) + (flat >> 3);
  bx = s & (GX - 1);
  by = (s / GX) & (GY - 1);
  bz = s / (GX * GY);
}

// T4 pipeline sync: wait with N loads still in flight, then raw barrier.
__device__ __forceinline__ void wait_bar_keep8() {
  asm volatile("s_waitcnt vmcnt(8)" ::: "memory");
  __builtin_amdgcn_s_barrier();
  __builtin_amdgcn_sched_barrier(0);
}
__device__ __forceinline__ void wait_bar_keep4() {
  asm volatile("s_waitcnt vmcnt(4)" ::: "memory");
  __builtin_amdgcn_s_barrier();
  __builtin_amdgcn_sched_barrier(0);
}
__device__ __forceinline__ void wait_bar_drain() {
  asm volatile("s_waitcnt vmcnt(0)" ::: "memory");
  __builtin_amdgcn_s_barrier();
  __builtin_amdgcn_sched_barrier(0);
}
__device__ __forceinline__ void end_bar() {
  __builtin_amdgcn_sched_barrier(0);
  __builtin_amdgcn_s_barrier();
}

// Fragment-linear stager (R8): LDS dest lane-linear, GLOBAL source permuted so
// each 16-row subtile lands as [chunk-group][chunk][row]; MFMA fragment read is
// subtile_base + h*1024 + lane*16 -> conflict-free.
template <int ROUNDS, int C>
__device__ __forceinline__ void stageF(const char* g, long row0, long ldb,
                                       long k0b, char* l, int tid) {
#pragma unroll
  for (int r = 0; r < ROUNDS; ++r) {
    int s = r * 256 + tid;
    int sub = s / (16 * C);
    int t = s % (16 * C);
    int h = t >> 6;
    int lk = (t >> 4) & 3;
    int lr = t & 15;
    gl_lds16(g + (row0 + sub * 16 + lr) * ldb + k0b + (h * 4 + lk) * 16,
             l + s * 16);
  }
}

// ---------------------------------------------------------------- convert W
__global__ void __launch_bounds__(256) convert_w(
    const float* __restrict__ Wq, const float* __restrict__ Wk,
    const float* __restrict__ Wv,
    u8* __restrict__ wq0, u8* __restrict__ wq1,
    u8* __restrict__ wk0, u8* __restrict__ wk1, u16* __restrict__ wvh) {
  long b = blockIdx.x;
  if (b < 2048) {
    int which = (int)(b >> 10);  // 0=q, 1=k
    const float* src = which ? Wk : Wq;
    u8* o0 = which ? wk0 : wq0;
    u8* o1 = which ? wk1 : wq1;
    long i = (b & 1023) * 256 + threadIdx.x;
    f32x4 v = ((const f32x4*)src)[i];
    u32 p0 = 0, p1 = 0;
#pragma unroll
    for (int j = 0; j < 4; ++j) {
      int d0, d1;
      dig2(v[j], WC, WCI, WFI, d0, d1);
      p0 |= ((u32)(d0 & 255)) << (8 * j);
      p1 |= ((u32)(d1 & 255)) << (8 * j);
    }
    ((u32*)o0)[i] = p0;
    ((u32*)o1)[i] = p1;
  } else {
    long i = (b - 2048) * 256 + threadIdx.x;
    f32x4 v = ((const f32x4*)Wv)[i];
    u16x4 h;
#pragma unroll
    for (int j = 0; j < 4; ++j) h[j] = f2bf(v[j]);
    ((u16x4*)wvh)[i] = h;
  }
}

// ---------------------------------------------------------------- transpose W digits
__global__ void __launch_bounds__(256) transpose_w(
    const u8* __restrict__ wq0, const u8* __restrict__ wq1,
    const u8* __restrict__ wk0, const u8* __restrict__ wk1,
    u8* __restrict__ wqT0, u8* __restrict__ wqT1,
    u8* __restrict__ wkT0, u8* __restrict__ wkT1) {
  __shared__ u8 T[64][68];
  int a = blockIdx.z;
  const u8* src = a == 0 ? wq0 : a == 1 ? wq1 : a == 2 ? wk0 : wk1;
  u8* dst = a == 0 ? wqT0 : a == 1 ? wqT1 : a == 2 ? wkT0 : wkT1;
  int bi = blockIdx.y, bj = blockIdx.x;
  int t = threadIdx.x, r = t >> 2, c4 = t & 3;
  const u32* s = (const u32*)(src + (long)(bi * 64 + r) * 1024 + bj * 64 + c4 * 16);
  u32 v0 = s[0], v1 = s[1], v2 = s[2], v3 = s[3];
  u32* trow = (u32*)&T[r][c4 * 16];
  trow[0] = v0; trow[1] = v1; trow[2] = v2; trow[3] = v3;
  __syncthreads();
  u32 o[4] = {0, 0, 0, 0};
#pragma unroll
  for (int j = 0; j < 16; ++j)
    o[j >> 2] |= ((u32)T[c4 * 16 + j][r]) << (8 * (j & 3));
  u32* d = (u32*)(dst + (long)(bj * 64 + r) * 1024 + bi * 64 + c4 * 16);
  d[0] = o[0]; d[1] = o[1]; d[2] = o[2]; d[3] = o[3];
}

// ---------------------------------------------------------------- gvec
// gq = Wq^T bk, gk = Wk^T bq (from digit arrays; digit residual 2^-18 -> err
// utterly negligible), c = bq.bk
__global__ void __launch_bounds__(256) gvec_kernel(
    const u8* __restrict__ wqT0, const u8* __restrict__ wqT1,
    const u8* __restrict__ wkT0, const u8* __restrict__ wkT1,
    const float* __restrict__ bq, const float* __restrict__ bk,
    float* __restrict__ gq, float* __restrict__ gk, float* __restrict__ cbuf) {
  __shared__ float sbq[1024], sbk[1024];
  int tid = threadIdx.x;
  ((f32x4*)sbq)[tid] = ((const f32x4*)bq)[tid];
  ((f32x4*)sbk)[tid] = ((const f32x4*)bk)[tid];
  __syncthreads();
  int wave = tid >> 6, lane = tid & 63;
#pragma unroll
  for (int rr = 0; rr < 2; ++rr) {
    int d = blockIdx.x * 8 + wave * 2 + rr;
    i8x16 a0 = *(const i8x16*)(wqT0 + (long)d * 1024 + lane * 16);
    i8x16 a1 = *(const i8x16*)(wqT1 + (long)d * 1024 + lane * 16);
    i8x16 c0 = *(const i8x16*)(wkT0 + (long)d * 1024 + lane * 16);
    i8x16 c1 = *(const i8x16*)(wkT1 + (long)d * 1024 + lane * 16);
    float sq = 0.f, sk = 0.f;
#pragma unroll
    for (int j = 0; j < 16; ++j) {
      sq += ((float)a0[j] * WC + (float)a1[j] * W1S) * sbk[lane * 16 + j];
      sk += ((float)c0[j] * WC + (float)c1[j] * W1S) * sbq[lane * 16 + j];
    }
#pragma unroll
    for (int off = 32; off >= 1; off >>= 1) {
      sq += __shfl_xor(sq, off);
      sk += __shfl_xor(sk, off);
    }
    if (!lane) { gq[d] = sq; gk[d] = sk; }
  }
  if (blockIdx.x == 0 && wave == 0) {
    float c = 0.f;
#pragma unroll
    for (int j = 0; j < 16; ++j) c += sbq[lane * 16 + j] * sbk[lane * 16 + j];
#pragma unroll
    for (int off = 32; off >= 1; off >>= 1) c += __shfl_xor(c, off);
    if (!lane) cbuf[0] = c;
  }
}

// ---------------------------------------------------------------- convert x
// digits + bf16 + per-row u = x.gq + c, w = x.gk
__global__ void __launch_bounds__(256) convert_x(
    const float* __restrict__ x, const float* __restrict__ gq,
    const float* __restrict__ gk, const float* __restrict__ cbuf,
    u16* __restrict__ xh, u8* __restrict__ xd0, u8* __restrict__ xd1,
    float* __restrict__ ubuf, float* __restrict__ wbuf) {
  long b = blockIdx.x;
  int tid = threadIdx.x;
  long i = b * 256 + tid;
  f32x4 v = ((const f32x4*)x)[i];
  u16x4 h;
  u32 p0 = 0, p1 = 0;
#pragma unroll
  for (int j = 0; j < 4; ++j) {
    h[j] = f2bf(v[j]);
    int d0, d1;
    dig2(v[j], XC, XCI, XFI, d0, d1);
    p0 |= ((u32)(d0 & 255)) << (8 * j);
    p1 |= ((u32)(d1 & 255)) << (8 * j);
  }
  ((u16x4*)xh)[i] = h;
  ((u32*)xd0)[i] = p0;
  ((u32*)xd1)[i] = p1;

  f32x4 g4 = ((const f32x4*)gq)[tid];
  f32x4 k4 = ((const f32x4*)gk)[tid];
  float pu = v[0] * g4[0] + v[1] * g4[1] + v[2] * g4[2] + v[3] * g4[3];
  float pw = v[0] * k4[0] + v[1] * k4[1] + v[2] * k4[2] + v[3] * k4[3];
#pragma unroll
  for (int off = 32; off >= 1; off >>= 1) {
    pu += __shfl_xor(pu, off);
    pw += __shfl_xor(pw, off);
  }
  __shared__ float ru[4], rw[4];
  int wave = tid >> 6, lane = tid & 63;
  if (!lane) { ru[wave] = pu; rw[wave] = pw; }
  __syncthreads();
  if (!tid) {
    ubuf[b] = ru[0] + ru[1] + ru[2] + ru[3] + cbuf[0];
    wbuf[b] = rw[0] + rw[1] + rw[2] + rw[3];
  }
}

// ---------------------------------------------------------------- G partial GEMM
// G_ij = sum_d Wq[d,i] Wk[d,j]: A=wqT, B=wkT, K-split 4 (256 each), f32 partial
// written TRANSPOSED: Gpart[z][j][i] so the reduce+digitize is coalesced and
// Gt[n=j][k=i] is row-major-K for t_gemm's B side.
__global__ void __launch_bounds__(256) g_part(
    const u8* __restrict__ wqT0, const u8* __restrict__ wqT1,
    const u8* __restrict__ wkT0, const u8* __restrict__ wkT1,
    float* __restrict__ Gpart) {
  __shared__ char lds[65536];
  const int tid = threadIdx.x;
  const int bx = blockIdx.x, by = blockIdx.y, bz = blockIdx.z;
  const long m0 = (long)by * 128;
  const int n0 = bx * 128;
  const int k00 = bz * 256;
  const int wave = tid >> 6, lane = tid & 63;
  const int wm = wave >> 1, wn = wave & 1;
  const int lr = lane & 15, lk = lane >> 4;

  i32x4 accM[4][4] = {};
  i32x4 accX[4][4] = {};
  i32x4 accY[4][4] = {};

  auto stage = [&](char* L, int kk) {
    stageF<2, 4>((const char*)wqT0, m0, 1024, kk, L + 0, tid);
    stageF<2, 4>((const char*)wqT1, m0, 1024, kk, L + 8192, tid);
    stageF<2, 4>((const char*)wkT0, n0, 1024, kk, L + 16384, tid);
    stageF<2, 4>((const char*)wkT1, n0, 1024, kk, L + 24576, tid);
  };
  auto compute = [&](const char* L) {
    i32x4 b0[4], b1[4];
#pragma unroll
    for (int nt = 0; nt < 4; ++nt) {
      int rb = (wn * 4 + nt) * 1024 + lane * 16;
      b0[nt] = *(const i32x4*)(L + 16384 + rb);
      b1[nt] = *(const i32x4*)(L + 24576 + rb);
    }
    __builtin_amdgcn_s_setprio(1);
#pragma unroll
    for (int mt = 0; mt < 4; ++mt) {
      int ra = (wm * 4 + mt) * 1024 + lane * 16;
      i32x4 a0 = *(const i32x4*)(L + ra);
      i32x4 a1 = *(const i32x4*)(L + 8192 + ra);
#pragma unroll
      for (int nt = 0; nt < 4; ++nt) {
        accM[mt][nt] = mfma_i8(a0, b0[nt], accM[mt][nt]);
        accX[mt][nt] = mfma_i8(a0, b1[nt], accX[mt][nt]);
        accX[mt][nt] = mfma_i8(a1, b0[nt], accX[mt][nt]);
        accY[mt][nt] = mfma_i8(a1, b1[nt], accY[mt][nt]);
      }
    }
    __builtin_amdgcn_s_setprio(0);
  };

  stage(lds, k00);
  for (int t = 0; t < 3; ++t) {
    char* L = lds + (t & 1) * 32768;
    stage(lds + ((t + 1) & 1) * 32768, k00 + (t + 1) * 64);
    wait_bar_keep8();
    compute(L);
    end_bar();
  }
  {
    char* L = lds + 32768;  // t=3 buffer
    wait_bar_drain();
    compute(L);
  }

#pragma unroll
  for (int mt = 0; mt < 4; ++mt)
#pragma unroll
    for (int nt = 0; nt < 4; ++nt) {
      int e = n0 + wn * 64 + nt * 16 + lr;
      int gmb = (int)m0 + wm * 64 + mt * 16 + lk * 4;
      f32x4 o;
#pragma unroll
      for (int r = 0; r < 4; ++r)
        o[r] = (float)accM[mt][nt][r] * SG00 + (float)accX[mt][nt][r] * SG01 +
               (float)accY[mt][nt][r] * SG11;
      *(f32x4*)(Gpart + ((long)bz << 20) + (long)e * 1024 + gmb) = o;
    }
}

// ---------------------------------------------------------------- G reduce+digitize
__global__ void __launch_bounds__(256) g_reduce(const float* __restrict__ Gpart,
                                                u8* __restrict__ Gt0,
                                                u8* __restrict__ Gt1) {
  int n = blockIdx.x, tid = threadIdx.x;
  long o = (long)n * 1024 + tid * 4;
  f32x4 v = *(const f32x4*)(Gpart + o);
  f32x4 v1 = *(const f32x4*)(Gpart + (1L << 20) + o);
  f32x4 v2 = *(const f32x4*)(Gpart + (2L << 20) + o);
  f32x4 v3 = *(const f32x4*)(Gpart + (3L << 20) + o);
#pragma unroll
  for (int j = 0; j < 4; ++j) v[j] = v[j] + v1[j] + v2[j] + v3[j];
  u32 p0 = 0, p1 = 0;
#pragma unroll
  for (int j = 0; j < 4; ++j) {
    int d0, d1;
    dig2(v[j], WC, WCI, WFI, d0, d1);
    p0 |= ((u32)(d0 & 255)) << (8 * j);
    p1 |= ((u32)(d1 & 255)) << (8 * j);
  }
  ((u32*)Gt0)[n * 256 + tid] = p0;
  ((u32*)Gt1)[n * 256 + tid] = p1;
}

// ---------------------------------------------------------------- t GEMM (t = x G)
// identical structure to the old qk projection, half the grid, no bias.
__global__ void __launch_bounds__(256) t_gemm(
    const u8* __restrict__ xd0, const u8* __restrict__ xd1,
    const u8* __restrict__ Gt0, const u8* __restrict__ Gt1,
    u8* __restrict__ t0, u8* __restrict__ t1) {
  __shared__ char lds[65536];
  const int tid = threadIdx.x;
  int bx, by, bz;
  xcd_swz<8, 64, 1>(bx, by, bz);
  const long m0 = (long)by * 128;
  const int n0 = bx * 128;
  const int wave = tid >> 6, lane = tid & 63;
  const int wm = wave >> 1, wn = wave & 1;
  const int lr = lane & 15, lk = lane >> 4;

  i32x4 accM[4][4] = {};
  i32x4 accX[4][4] = {};
  i32x4 accY[4][4] = {};

  auto stage = [&](char* L, int kk) {
    stageF<2, 4>((const char*)xd0, m0, Dd, kk, L + 0, tid);
    stageF<2, 4>((const char*)xd1, m0, Dd, kk, L + 8192, tid);
    stageF<2, 4>((const char*)Gt0, n0, 1024, kk, L + 16384, tid);
    stageF<2, 4>((const char*)Gt1, n0, 1024, kk, L + 24576, tid);
  };
  auto compute = [&](const char* L) {
    i32x4 b0[4], b1[4];
#pragma unroll
    for (int nt = 0; nt < 4; ++nt) {
      int rb = (wn * 4 + nt) * 1024 + lane * 16;
      b0[nt] = *(const i32x4*)(L + 16384 + rb);
      b1[nt] = *(const i32x4*)(L + 24576 + rb);
    }
    __builtin_amdgcn_s_setprio(1);
#pragma unroll
    for (int mt = 0; mt < 4; ++mt) {
      int ra = (wm * 4 + mt) * 1024 + lane * 16;
      i32x4 a0 = *(const i32x4*)(L + ra);
      i32x4 a1 = *(const i32x4*)(L + 8192 + ra);
#pragma unroll
      for (int nt = 0; nt < 4; ++nt) {
        accM[mt][nt] = mfma_i8(a0, b0[nt], accM[mt][nt]);
        accX[mt][nt] = mfma_i8(a0, b1[nt], accX[mt][nt]);
        accX[mt][nt] = mfma_i8(a1, b0[nt], accX[mt][nt]);
        accY[mt][nt] = mfma_i8(a1, b1[nt], accY[mt][nt]);
      }
    }
    __builtin_amdgcn_s_setprio(0);
  };

  stage(lds, 0);
  for (int t = 0; t < Dd / 64 - 1; ++t) {
    char* L = lds + (t & 1) * 32768;
    stage(lds + ((t + 1) & 1) * 32768, (t + 1) * 64);
    wait_bar_keep8();
    compute(L);
    end_bar();
  }
  {
    char* L = lds + ((Dd / 64 - 1) & 1) * 32768;
    wait_bar_drain();
    compute(L);
  }

#pragma unroll
  for (int mt = 0; mt < 4; ++mt)
#pragma unroll
    for (int nt = 0; nt < 4; ++nt)
#pragma unroll
      for (int r = 0; r < 4; ++r) {
        long gm = m0 + wm * 64 + mt * 16 + lk * 4 + r;
        int e = n0 + wn * 64 + nt * 16 + lr;
        float v = (float)accM[mt][nt][r] * SM_P +
                  (float)accX[mt][nt][r] * SX_P +
                  (float)accY[mt][nt][r] * SY_P;
        int d0, d1;
        dig2(v, XC, XCI, XFI, d0, d1);
        long idx = gm * Dd + e;
        t0[idx] = (u8)d0;
        t1[idx] = (u8)d1;
      }
}

// ---------------------------------------------------------------- v GEMM
__global__ void __launch_bounds__(256) v_gemm(
    const u16* __restrict__ xh, const u16* __restrict__ wvh,
    const float* __restrict__ bv, u16* __restrict__ vt) {
  __shared__ char lds[32768];
  const int tid = threadIdx.x;
  int bx, by, bz;
  xcd_swz<8, 64, 1>(bx, by, bz);
  const long m0 = (long)by * 128;
  const int n0 = bx * 128;
  const int wave = tid >> 6, lane = tid & 63;
  const int wm = wave >> 1, wn = wave & 1;
  const int lr = lane & 15, lk = lane >> 4;

  f32x4 acc[4][4] = {};

  auto stage = [&](char* L, int k0) {
    stageF<2, 4>((const char*)xh, m0, (long)Dd * 2, (long)k0 * 2, L + 0, tid);
    stageF<2, 4>((const char*)wvh, n0, (long)Dd * 2, (long)k0 * 2, L + 8192, tid);
  };
  auto compute = [&](const char* L) {
    bf16x8 af[4], bfr[4];
#pragma unroll
    for (int i = 0; i < 4; ++i) {
      int ra = (wm * 4 + i) * 1024 + lane * 16;
      int rb = (wn * 4 + i) * 1024 + lane * 16;
      af[i] = frag_ld(L + ra);
      bfr[i] = frag_ld(L + 8192 + rb);
    }
    __builtin_amdgcn_s_setprio(1);
#pragma unroll
    for (int mt = 0; mt < 4; ++mt)
#pragma unroll
      for (int nt = 0; nt < 4; ++nt)
        acc[mt][nt] = mfma_bf16(af[mt], bfr[nt], acc[mt][nt]);
    __builtin_amdgcn_s_setprio(0);
  };

  stage(lds, 0);
  for (int t = 0; t < Dd / 32 - 1; ++t) {
    char* L = lds + (t & 1) * 16384;
    stage(lds + ((t + 1) & 1) * 16384, (t + 1) * 32);
    wait_bar_keep4();
    compute(L);
    end_bar();
  }
  {
    char* L = lds + ((Dd / 32 - 1) & 1) * 16384;
    wait_bar_drain();
    compute(L);
  }

#pragma unroll
  for (int mt = 0; mt < 4; ++mt)
#pragma unroll
    for (int nt = 0; nt < 4; ++nt)
#pragma unroll
      for (int r = 0; r < 4; ++r) {
        long gm = m0 + wm * 64 + mt * 16 + lk * 4 + r;
        int e = n0 + wn * 64 + nt * 16 + lr;
        float v = acc[mt][nt][r] + bv[e];
        long b = gm >> 11, s = gm & 2047;
        vt[(b * Dd + e) * (long)Ss + s] = f2h(v);
      }
}

// ---------------------------------------------------------------- scores GEMM
// scores = t x^T + u[i] + w[j]  (u already includes c)
__global__ void __launch_bounds__(256) score_gemm(
    const u8* __restrict__ t0, const u8* __restrict__ t1,
    const u8* __restrict__ xd0, const u8* __restrict__ xd1,
    const float* __restrict__ ubuf, const float* __restrict__ wbuf,
    float* __restrict__ scores) {
  __shared__ char lds[65536];
  const int tid = threadIdx.x;
  int bx, by, bz;
  xcd_swz<16, 16, 4>(bx, by, bz);
  const int z = bz;  // batch
  const long base = (long)z * Ss * Dd;
  const long m0 = (long)by * 128;
  const int n0 = bx * 128;
  const int wave = tid >> 6, lane = tid & 63;
  const int wm = wave >> 1, wn = wave & 1;
  const int lr = lane & 15, lk = lane >> 4;

  i32x4 accM[4][4] = {};
  i32x4 accX[4][4] = {};
  i32x4 accY[4][4] = {};

  auto stage = [&](char* L, int kk) {
    stageF<2, 4>((const char*)t0 + base, m0, Dd, kk, L + 0, tid);
    stageF<2, 4>((const char*)t1 + base, m0, Dd, kk, L + 8192, tid);
    stageF<2, 4>((const char*)xd0 + base, n0, Dd, kk, L + 16384, tid);
    stageF<2, 4>((const char*)xd1 + base, n0, Dd, kk, L + 24576, tid);
  };
  auto compute = [&](const char* L) {
    i32x4 b0[4], b1[4];
#pragma unroll
    for (int nt = 0; nt < 4; ++nt) {
      int rb = (wn * 4 + nt) * 1024 + lane * 16;
      b0[nt] = *(const i32x4*)(L + 16384 + rb);
      b1[nt] = *(const i32x4*)(L + 24576 + rb);
    }
    __builtin_amdgcn_s_setprio(1);
#pragma unroll
    for (int mt = 0; mt < 4; ++mt) {
      int ra = (wm * 4 + mt) * 1024 + lane * 16;
      i32x4 a0 = *(const i32x4*)(L + ra);
      i32x4 a1 = *(const i32x4*)(L + 8192 + ra);
#pragma unroll
      for (int nt = 0; nt < 4; ++nt) {
        accM[mt][nt] = mfma_i8(a0, b0[nt], accM[mt][nt]);
        accX[mt][nt] = mfma_i8(a0, b1[nt], accX[mt][nt]);
        accX[mt][nt] = mfma_i8(a1, b0[nt], accX[mt][nt]);
        accY[mt][nt] = mfma_i8(a1, b1[nt], accY[mt][nt]);
      }
    }
    __builtin_amdgcn_s_setprio(0);
  };

  stage(lds, 0);
  for (int t = 0; t < Dd / 64 - 1; ++t) {
    char* L = lds + (t & 1) * 32768;
    stage(lds + ((t + 1) & 1) * 32768, (t + 1) * 64);
    wait_bar_keep8();
    compute(L);
    end_bar();
  }
  {
    char* L = lds + ((Dd / 64 - 1) & 1) * 32768;
    wait_bar_drain();
    compute(L);
  }

  float* srow = scores + (long)z * Ss * Ss;
#pragma unroll
  for (int mt = 0; mt < 4; ++mt)
#pragma unroll
    for (int nt = 0; nt < 4; ++nt)
#pragma unroll
      for (int r = 0; r < 4; ++r) {
        long i = m0 + wm * 64 + mt * 16 + lk * 4 + r;
        int j = n0 + wn * 64 + nt * 16 + lr;
        srow[i * Ss + j] = (float)accM[mt][nt][r] * S00 +
                           (float)accX[mt][nt][r] * S01 +
                           (float)accY[mt][nt][r] * S11 +
                           ubuf[(z << 11) + i] + wbuf[(z << 11) + j];
      }
}

// ---------------------------------------------------------------- softmax
__global__ void __launch_bounds__(256) softmax_rows(const float* __restrict__ scores,
                                                    u16* __restrict__ P) {
  const long r = blockIdx.x;
  const float* row = scores + r * Ss;
  u16* prow = P + r * Ss;
  const int t = threadIdx.x;
  const int wave = t >> 6, lane = t & 63;
  f32x4 v0 = ((const f32x4*)row)[t * 2];
  f32x4 v1 = ((const f32x4*)row)[t * 2 + 1];
  float a[8];
#pragma unroll
  for (int j = 0; j < 4; ++j) { a[j] = v0[j]; a[4 + j] = v1[j]; }

  float m = a[0];
#pragma unroll
  for (int j = 1; j < 8; ++j) m = fmaxf(m, a[j]);
#pragma unroll
  for (int off = 32; off >= 1; off >>= 1) m = fmaxf(m, __shfl_xor(m, off));
  __shared__ float red[4];
  if (lane == 0) red[wave] = m;
  __syncthreads();
  m = fmaxf(fmaxf(red[0], red[1]), fmaxf(red[2], red[3]));

  float e[8];
  float s = 0.f;
#pragma unroll
  for (int j = 0; j < 8; ++j) { e[j] = __expf(a[j] - m); s += e[j]; }
#pragma unroll
  for (int off = 32; off >= 1; off >>= 1) s += __shfl_xor(s, off);
  __syncthreads();
  if (lane == 0) red[wave] = s;
  __syncthreads();
  s = red[0] + red[1] + red[2] + red[3];
  float inv = 1.0f / s;

  u16x8 pk;
#pragma unroll
  for (int j = 0; j < 8; ++j) pk[j] = f2h(e[j] * inv);
  ((u16x8*)prow)[t] = pk;
}

// ---------------------------------------------------------------- PV GEMM
__global__ void __launch_bounds__(256) pv_gemm(const u16* __restrict__ P,
                                               const u16* __restrict__ vt,
                                               float* __restrict__ out) {
  __shared__ char lds[32768];
  const int tid = threadIdx.x;
  int bx, by, bz;
  xcd_swz<8, 16, 4>(bx, by, bz);
  const int z = bz;  // batch
  const u16* A = P + (long)z * Ss * Ss;
  const u16* Bp = vt + (long)z * Dd * Ss;
  const long m0 = (long)by * 128;
  const int n0 = bx * 128;

  const int wave = tid >> 6, lane = tid & 63;
  const int wm = wave >> 1, wn = wave & 1;
  const int lr = lane & 15, lk = lane >> 4;

  f32x4 acc[4][4] = {};

  auto stage = [&](char* L, int k0) {
    stageF<2, 4>((const char*)A, m0, (long)Ss * 2, (long)k0 * 2, L + 0, tid);
    stageF<2, 4>((const char*)Bp, n0, (long)Ss * 2, (long)k0 * 2, L + 8192, tid);
  };
  auto compute = [&](const char* L) {
    f16x8 af[4], bfr[4];
#pragma unroll
    for (int i = 0; i < 4; ++i) {
      int ra = (wm * 4 + i) * 1024 + lane * 16;
      int rb = (wn * 4 + i) * 1024 + lane * 16;
      af[i] = frag_ld_h(L + ra);
      bfr[i] = frag_ld_h(L + 8192 + rb);
    }
    __builtin_amdgcn_s_setprio(1);
#pragma unroll
    for (int mt = 0; mt < 4; ++mt)
#pragma unroll
      for (int nt = 0; nt < 4; ++nt)
        acc[mt][nt] = __builtin_amdgcn_mfma_f32_16x16x32_f16(af[mt], bfr[nt], acc[mt][nt], 0, 0, 0);
    __builtin_amdgcn_s_setprio(0);
  };

  stage(lds, 0);
  for (int t = 0; t < Ss / 32 - 1; ++t) {
    char* L = lds + (t & 1) * 16384;
    stage(lds + ((t + 1) & 1) * 16384, (t + 1) * 32);
    wait_bar_keep4();
    compute(L);
    end_bar();
  }
  {
    char* L = lds + ((Ss / 32 - 1) & 1) * 16384;
    wait_bar_drain();
    compute(L);
  }

  float* orow = out + (long)z * Ss * Dd;
#pragma unroll
  for (int mt = 0; mt < 4; ++mt)
#pragma unroll
    for (int nt = 0; nt < 4; ++nt)
#pragma unroll
      for (int r = 0; r < 4; ++r) {
        long i = m0 + wm * 64 + mt * 16 + lk * 4 + r;
        int e = n0 + wn * 64 + nt * 16 + lr;
        orow[i * Dd + e] = acc[mt][nt][r];
      }
}

// ---------------------------------------------------------------- launch
extern "C" void kernel_launch(void* const* d_in, const int* in_sizes, int n_in,
                              void* d_out, int out_size, void* d_ws, size_t ws_size,
                              hipStream_t stream) {
  const float* x = (const float*)d_in[0];
  const float* Wq = (const float*)d_in[1];
  const float* bq = (const float*)d_in[2];
  const float* Wk = (const float*)d_in[3];
  const float* bk = (const float*)d_in[4];
  const float* Wv = (const float*)d_in[5];
  const float* bv = (const float*)d_in[6];
  float* out = (float*)d_out;

  // workspace carve (~148 MiB, aliases noted; all writes happen strictly after
  // the aliased reader per the launch order below)
  char* p = (char*)d_ws;
  float* scores = (float*)p;                 // [0,64Mi)
  u16* xh = (u16*)p;                         // [0,16Mi)  dead after v_gemm
  u8* Gt0 = (u8*)p;                          // [0,1Mi)   written after v_gemm
  u8* Gt1 = (u8*)(p + (1L << 20));           // [1,2Mi)
  u16* wvh = (u16*)(p + (16L << 20));        // [16,18Mi) dead after v_gemm
  u8* xd0 = (u8*)(p + (64L << 20));
  u8* xd1 = (u8*)(p + (72L << 20));
  u8* t0 = (u8*)(p + (80L << 20));           // [80,88Mi)
  u8* t1 = (u8*)(p + (88L << 20));           // [88,96Mi)
  u8* wq0 = (u8*)(p + (80L << 20));          // alias: dead after transpose_w
  u8* wq1 = wq0 + (1L << 20);
  u8* wk0 = wq0 + (2L << 20);
  u8* wk1 = wq0 + (3L << 20);
  float* Gpart = (float*)(p + (80L << 20));  // alias: dead after g_reduce
  u16* Pbuf = (u16*)(p + (96L << 20));
  u16* vt = (u16*)(p + (128L << 20));
  u8* wqT0 = (u8*)(p + (144L << 20));
  u8* wqT1 = wqT0 + (1L << 20);
  u8* wkT0 = wqT0 + (2L << 20);
  u8* wkT1 = wqT0 + (3L << 20);
  float* gq = (float*)(p + (148L << 20));
  float* gk = gq + 1024;
  float* ubuf = gq + 2048;
  float* wbuf = ubuf + 8192;
  float* cbuf = wbuf + 8192;

  // 1. W digits + Wv bf16
  convert_w<<<dim3(3072), dim3(256), 0, stream>>>(Wq, Wk, Wv, wq0, wq1, wk0, wk1, wvh);
  // 2. transpose W digit arrays (for G = Wq^T Wk staging)
  transpose_w<<<dim3(16, 16, 4), dim3(256), 0, stream>>>(
      wq0, wq1, wk0, wk1, wqT0, wqT1, wkT0, wkT1);
  // 3. gq = Wq^T bk, gk = Wk^T bq, c = bq.bk
  gvec_kernel<<<dim3(128), dim3(256), 0, stream>>>(
      wqT0, wqT1, wkT0, wkT1, bq, bk, gq, gk, cbuf);
  // 4. x digits + bf16 + u,w row dots
  convert_x<<<dim3(8192), dim3(256), 0, stream>>>(
      x, gq, gk, cbuf, xh, xd0, xd1, ubuf, wbuf);
  // 5. v projection (reads xh, wvh -> both dead after)
  v_gemm<<<dim3(Dd / 128, Mtot / 128), dim3(256), 0, stream>>>(xh, wvh, bv, vt);
  // 6. G partials (K-split 4), writes over wq row-major digits (dead)
  g_part<<<dim3(8, 8, 4), dim3(256), 0, stream>>>(wqT0, wqT1, wkT0, wkT1, Gpart);
  // 7. reduce + digitize G (writes over xh head, dead)
  g_reduce<<<dim3(1024), dim3(256), 0, stream>>>(Gpart, Gt0, Gt1);
  // 8. t = x G (writes over Gpart, dead)
  t_gemm<<<dim3(Dd / 128, Mtot / 128), dim3(256), 0, stream>>>(
      xd0, xd1, Gt0, Gt1, t0, t1);
  // 9. scores = t x^T + u + w (writes over Gt/wvh, dead)
  score_gemm<<<dim3(Ss / 128, Ss / 128, Bb), dim3(256), 0, stream>>>(
      t0, t1, xd0, xd1, ubuf, wbuf, scores);
  // 10. softmax rows -> dense P
  softmax_rows<<<dim3(Bb * Ss), dim3(256), 0, stream>>>(scores, Pbuf);
  // 11. out = P @ v
  pv_gemm<<<dim3(Dd / 128, Ss / 128, Bb), dim3(256), 0, stream>>>(Pbuf, vt, out);
}